// Round 1
// baseline (517.968 us; speedup 1.0000x reference)
//
#include <hip/hip_runtime.h>
#include <hip/hip_bf16.h>
#include <stdint.h>

#define B_    16
#define C_    320
#define S_    4096
#define G_    32
#define LC    77
#define CTX   768
#define HEADS 8
#define HD    40

typedef __bf16 bf16x8_t __attribute__((ext_vector_type(8)));
typedef float  f32x4_t  __attribute__((ext_vector_type(4)));

__device__ __forceinline__ unsigned short f2bf(float f) {
    union { float f; unsigned int u; } v; v.f = f;
    unsigned int r = v.u + 0x7fffu + ((v.u >> 16) & 1u);
    return (unsigned short)(r >> 16);
}
__device__ __forceinline__ float bf2f(unsigned short h) {
    union { unsigned int u; float f; } v; v.u = ((unsigned int)h) << 16;
    return v.f;
}
__device__ __forceinline__ void unpack8(uint4 p, float* f) {
    f[0] = bf2f(p.x & 0xffffu); f[1] = bf2f(p.x >> 16);
    f[2] = bf2f(p.y & 0xffffu); f[3] = bf2f(p.y >> 16);
    f[4] = bf2f(p.z & 0xffffu); f[5] = bf2f(p.z >> 16);
    f[6] = bf2f(p.w & 0xffffu); f[7] = bf2f(p.w >> 16);
}

// ---------------------------------------------------------------- GN stats
// one block per (b,g); group data is contiguous: 10 channels * 4096 = 40960 f32
__global__ __launch_bounds__(256) void gn_stats(const float* __restrict__ x,
                                                float2* __restrict__ mr) {
    int bg = blockIdx.x;
    const float4* p = (const float4*)(x + (size_t)bg * 40960);
    float s = 0.f, s2 = 0.f;
    for (int i = threadIdx.x; i < 10240; i += 256) {
        float4 v = p[i];
        s  += v.x + v.y + v.z + v.w;
        s2 += v.x * v.x + v.y * v.y + v.z * v.z + v.w * v.w;
    }
    for (int o = 32; o; o >>= 1) {
        s  += __shfl_down(s, o);
        s2 += __shfl_down(s2, o);
    }
    __shared__ float2 red[4];
    int lane = threadIdx.x & 63, wid = threadIdx.x >> 6;
    if (lane == 0) red[wid] = make_float2(s, s2);
    __syncthreads();
    if (threadIdx.x == 0) {
        float a = 0.f, c = 0.f;
        for (int i = 0; i < 4; i++) { a += red[i].x; c += red[i].y; }
        float mean = a / 40960.f;
        float var  = c / 40960.f - mean * mean;
        mr[bg] = make_float2(mean, rsqrtf(var + 1e-5f));
    }
}

// ---------------------------------------------------------------- weight cast
__global__ __launch_bounds__(256) void castw(const float* __restrict__ s,
                                             unsigned short* __restrict__ d) {
    int i = blockIdx.x * 256 + threadIdx.x;
    float4 v = ((const float4*)s)[i];
    ushort4 o;
    o.x = f2bf(v.x); o.y = f2bf(v.y); o.z = f2bf(v.z); o.w = f2bf(v.w);
    ((ushort4*)d)[i] = o;
}

// ---------------------------------------------------------------- normalize + transpose
// x [B,C,S] f32 -> tokens [B,S,C] bf16, with groupnorm applied
__global__ __launch_bounds__(256) void norm_tr(const float* __restrict__ x,
                                               const float2* __restrict__ mr,
                                               const float* __restrict__ gns,
                                               const float* __restrict__ gnb,
                                               unsigned short* __restrict__ tok) {
    int s0 = blockIdx.x * 32, c0 = blockIdx.y * 32, b = blockIdx.z;
    __shared__ unsigned short t[32][33];
    int tx = threadIdx.x & 31, ty = threadIdx.x >> 5;
    #pragma unroll
    for (int i = 0; i < 4; i++) {
        int cl = i * 8 + ty;
        int c = c0 + cl;
        float2 m = mr[b * 32 + c / 10];
        float v = x[((size_t)(b * 320 + c)) * 4096 + s0 + tx];
        v = (v - m.x) * m.y * gns[c] + gnb[c];
        t[cl][tx] = f2bf(v);
    }
    __syncthreads();
    #pragma unroll
    for (int i = 0; i < 4; i++) {
        int sl = i * 8 + ty;
        tok[((size_t)b * 4096 + s0 + sl) * 320 + c0 + tx] = t[tx][sl];
    }
}

// ---------------------------------------------------------------- GEMM core (64x64 tile, K=320)
// A [.. x 320] bf16 row-major, W [320 x 320] bf16 row-major ([N][K]) -> acc 2x2 frags
__device__ __forceinline__ void gemm_core(const unsigned short* __restrict__ Ab,
                                          const unsigned short* __restrict__ Wb,
                                          unsigned short la[64][32],
                                          unsigned short lb[64][32],
                                          f32x4_t acc[2][2]) {
    int tid = threadIdx.x, lane = tid & 63, wid = tid >> 6;
    int wm = wid >> 1, wn = wid & 1;
    int lr = tid >> 2, lc = (tid & 3) * 8;
    int fr = lane & 15, kk = (lane >> 4) * 8;
    for (int k0 = 0; k0 < 320; k0 += 32) {
        *(uint4*)&la[lr][lc] = *(const uint4*)&Ab[(size_t)lr * 320 + k0 + lc];
        *(uint4*)&lb[lr][lc] = *(const uint4*)&Wb[(size_t)lr * 320 + k0 + lc];
        __syncthreads();
        bf16x8_t a0 = *(const bf16x8_t*)&la[wm * 32 + fr][kk];
        bf16x8_t a1 = *(const bf16x8_t*)&la[wm * 32 + 16 + fr][kk];
        bf16x8_t b0 = *(const bf16x8_t*)&lb[wn * 32 + fr][kk];
        bf16x8_t b1 = *(const bf16x8_t*)&lb[wn * 32 + 16 + fr][kk];
        acc[0][0] = __builtin_amdgcn_mfma_f32_16x16x32_bf16(a0, b0, acc[0][0], 0, 0, 0);
        acc[0][1] = __builtin_amdgcn_mfma_f32_16x16x32_bf16(a0, b1, acc[0][1], 0, 0, 0);
        acc[1][0] = __builtin_amdgcn_mfma_f32_16x16x32_bf16(a1, b0, acc[1][0], 0, 0, 0);
        acc[1][1] = __builtin_amdgcn_mfma_f32_16x16x32_bf16(a1, b1, acc[1][1], 0, 0, 0);
        __syncthreads();
    }
}

// Q projection: tokens [B,S,320] -> q [B,S,320] bf16
__global__ __launch_bounds__(256) void gemm_qproj(const unsigned short* __restrict__ A,
                                                  const unsigned short* __restrict__ W,
                                                  unsigned short* __restrict__ Q) {
    __shared__ unsigned short la[64][32], lb[64][32];
    int bm = blockIdx.x, bn = blockIdx.y, b = blockIdx.z;
    const unsigned short* Ab = A + ((size_t)b * S_ + bm * 64) * 320;
    const unsigned short* Wb = W + (size_t)bn * 64 * 320;
    f32x4_t acc[2][2] = {};
    gemm_core(Ab, Wb, la, lb, acc);
    int tid = threadIdx.x, lane = tid & 63, wid = tid >> 6;
    int wm = wid >> 1, wn = wid & 1;
    int fr = lane & 15, rg = (lane >> 4) * 4;
    #pragma unroll
    for (int mf = 0; mf < 2; mf++)
        #pragma unroll
        for (int nf = 0; nf < 2; nf++)
            #pragma unroll
            for (int r = 0; r < 4; r++) {
                int row = bm * 64 + wm * 32 + mf * 16 + rg + r;
                int col = bn * 64 + wn * 32 + nf * 16 + fr;
                Q[((size_t)b * S_ + row) * 320 + col] = f2bf(acc[mf][nf][r]);
            }
}

// Output projection: attn_out [B,S,320] @ Wo^T + bo + residual -> out [B,C,S] f32
__global__ __launch_bounds__(256) void gemm_oproj(const unsigned short* __restrict__ A,
                                                  const unsigned short* __restrict__ W,
                                                  const float* __restrict__ bo,
                                                  const float* __restrict__ resid,
                                                  float* __restrict__ out) {
    __shared__ unsigned short la[64][32], lb[64][32];
    __shared__ float lt[64][65];
    int bm = blockIdx.x, bn = blockIdx.y, b = blockIdx.z;
    const unsigned short* Ab = A + ((size_t)b * S_ + bm * 64) * 320;
    const unsigned short* Wb = W + (size_t)bn * 64 * 320;
    f32x4_t acc[2][2] = {};
    gemm_core(Ab, Wb, la, lb, acc);
    int tid = threadIdx.x, lane = tid & 63, wid = tid >> 6;
    int wm = wid >> 1, wn = wid & 1;
    int fr = lane & 15, rg = (lane >> 4) * 4;
    #pragma unroll
    for (int mf = 0; mf < 2; mf++)
        #pragma unroll
        for (int nf = 0; nf < 2; nf++)
            #pragma unroll
            for (int r = 0; r < 4; r++)
                lt[wm * 32 + mf * 16 + rg + r][wn * 32 + nf * 16 + fr] = acc[mf][nf][r];
    __syncthreads();
    #pragma unroll
    for (int p = 0; p < 16; p++) {
        int nl = p * 4 + (tid >> 6);
        int sl = tid & 63;
        int n = bn * 64 + nl, s = bm * 64 + sl;
        size_t idx = ((size_t)b * 320 + n) * 4096 + s;
        out[idx] = lt[sl][nl] + bo[n] + resid[idx];
    }
}

// ---------------------------------------------------------------- K/V projection (small)
// one block per (l, b): k[b,l,e] = ctx[b,l,:] . Wk[e,:], v likewise
__global__ __launch_bounds__(256) void kvproj(const float* __restrict__ ctx,
                                              const unsigned short* __restrict__ wk,
                                              const unsigned short* __restrict__ wv,
                                              unsigned short* __restrict__ k,
                                              unsigned short* __restrict__ v) {
    int l = blockIdx.x, b = blockIdx.y;
    __shared__ float cl[CTX];
    const float* cp = ctx + ((size_t)b * LC + l) * CTX;
    for (int i = threadIdx.x; i < CTX; i += 256) cl[i] = cp[i];
    __syncthreads();
    for (int e = threadIdx.x; e < 640; e += 256) {
        const unsigned short* w;
        unsigned short* dst;
        if (e < 320) { w = wk + (size_t)e * CTX;        dst = k + ((size_t)b * LC + l) * 320 + e; }
        else         { w = wv + (size_t)(e - 320) * CTX; dst = v + ((size_t)b * LC + l) * 320 + (e - 320); }
        float acc = 0.f;
        for (int kk = 0; kk < CTX; kk += 8) {
            uint4 pw = *(const uint4*)&w[kk];
            float wf[8]; unpack8(pw, wf);
            #pragma unroll
            for (int j = 0; j < 8; j++) acc += wf[j] * cl[kk + j];
        }
        *dst = f2bf(acc);
    }
}

// ---------------------------------------------------------------- attention
// one thread per q row; K/V head-slice staged in LDS (f32); two-pass softmax
__global__ __launch_bounds__(256) void attn(const unsigned short* __restrict__ q,
                                            const unsigned short* __restrict__ k,
                                            const unsigned short* __restrict__ v,
                                            unsigned short* __restrict__ o) {
    int st = blockIdx.x, h = blockIdx.y, b = blockIdx.z;
    __shared__ float kl[LC][HD];
    __shared__ float vl[LC][HD];
    for (int idx = threadIdx.x; idx < LC * 5; idx += 256) {
        int l = idx / 5, seg = idx % 5;
        size_t base = ((size_t)b * LC + l) * 320 + h * HD + seg * 8;
        float tmp[8];
        unpack8(*(const uint4*)&k[base], tmp);
        #pragma unroll
        for (int j = 0; j < 8; j++) kl[l][seg * 8 + j] = tmp[j];
        unpack8(*(const uint4*)&v[base], tmp);
        #pragma unroll
        for (int j = 0; j < 8; j++) vl[l][seg * 8 + j] = tmp[j];
    }
    __syncthreads();
    int s = st * 256 + threadIdx.x;
    const unsigned short* qp = q + ((size_t)(b * S_ + s)) * 320 + h * HD;
    const float scale = 0.15811388300841898f;  // 1/sqrt(40)
    float qr[HD];
    #pragma unroll
    for (int seg = 0; seg < 5; seg++) {
        float tmp[8];
        unpack8(*(const uint4*)&qp[seg * 8], tmp);
        #pragma unroll
        for (int j = 0; j < 8; j++) qr[seg * 8 + j] = tmp[j] * scale;
    }
    float m = -1e30f;
    for (int l = 0; l < LC; l++) {
        const float4* kr = (const float4*)kl[l];
        float sc = 0.f;
        #pragma unroll
        for (int d4 = 0; d4 < 10; d4++) {
            float4 kv4 = kr[d4];
            sc += qr[d4 * 4 + 0] * kv4.x + qr[d4 * 4 + 1] * kv4.y
                + qr[d4 * 4 + 2] * kv4.z + qr[d4 * 4 + 3] * kv4.w;
        }
        m = fmaxf(m, sc);
    }
    float sum = 0.f;
    float outr[HD];
    #pragma unroll
    for (int d = 0; d < HD; d++) outr[d] = 0.f;
    for (int l = 0; l < LC; l++) {
        const float4* kr = (const float4*)kl[l];
        float sc = 0.f;
        #pragma unroll
        for (int d4 = 0; d4 < 10; d4++) {
            float4 kv4 = kr[d4];
            sc += qr[d4 * 4 + 0] * kv4.x + qr[d4 * 4 + 1] * kv4.y
                + qr[d4 * 4 + 2] * kv4.z + qr[d4 * 4 + 3] * kv4.w;
        }
        float p = __expf(sc - m);
        sum += p;
        const float4* vr = (const float4*)vl[l];
        #pragma unroll
        for (int d4 = 0; d4 < 10; d4++) {
            float4 vv4 = vr[d4];
            outr[d4 * 4 + 0] += p * vv4.x; outr[d4 * 4 + 1] += p * vv4.y;
            outr[d4 * 4 + 2] += p * vv4.z; outr[d4 * 4 + 3] += p * vv4.w;
        }
    }
    float inv = 1.f / sum;
    unsigned short* op = o + ((size_t)(b * S_ + s)) * 320 + h * HD;
    #pragma unroll
    for (int seg = 0; seg < 5; seg++) {
        uint4 pk;
        unsigned int w0 = f2bf(outr[seg * 8 + 0] * inv) | ((unsigned int)f2bf(outr[seg * 8 + 1] * inv) << 16);
        unsigned int w1 = f2bf(outr[seg * 8 + 2] * inv) | ((unsigned int)f2bf(outr[seg * 8 + 3] * inv) << 16);
        unsigned int w2 = f2bf(outr[seg * 8 + 4] * inv) | ((unsigned int)f2bf(outr[seg * 8 + 5] * inv) << 16);
        unsigned int w3 = f2bf(outr[seg * 8 + 6] * inv) | ((unsigned int)f2bf(outr[seg * 8 + 7] * inv) << 16);
        pk.x = w0; pk.y = w1; pk.z = w2; pk.w = w3;
        *(uint4*)&op[seg * 8] = pk;
    }
}

// ---------------------------------------------------------------- launch
extern "C" void kernel_launch(void* const* d_in, const int* in_sizes, int n_in,
                              void* d_out, int out_size, void* d_ws, size_t ws_size,
                              hipStream_t stream) {
    const float* x    = (const float*)d_in[0];
    const float* ctx  = (const float*)d_in[1];
    const float* Wq   = (const float*)d_in[2];
    const float* Wk   = (const float*)d_in[3];
    const float* Wv   = (const float*)d_in[4];
    const float* Wo   = (const float*)d_in[5];
    const float* bo   = (const float*)d_in[6];
    const float* gns  = (const float*)d_in[7];
    const float* gnb  = (const float*)d_in[8];
    float* out = (float*)d_out;

    char* ws = (char*)d_ws;
    // workspace layout (all offsets 256B aligned)
    float2*         mr    = (float2*)(ws + 0);            //   4,096 B
    unsigned short* wq_bf = (unsigned short*)(ws + 4096);       // 204,800
    unsigned short* wk_bf = (unsigned short*)(ws + 208896);     // 491,520
    unsigned short* wv_bf = (unsigned short*)(ws + 700416);     // 491,520
    unsigned short* wo_bf = (unsigned short*)(ws + 1191936);    // 204,800
    unsigned short* k_bf  = (unsigned short*)(ws + 1396736);    // 788,480
    unsigned short* v_bf  = (unsigned short*)(ws + 2185216);    // 788,480
    unsigned short* tok   = (unsigned short*)(ws + 2973696);    // 41,943,040 (reused as attn_out)
    unsigned short* q_bf  = (unsigned short*)(ws + 44916736);   // 41,943,040
    // total: 86,859,776 B

    gn_stats<<<512, 256, 0, stream>>>(x, mr);
    castw<<<100, 256, 0, stream>>>(Wq, wq_bf);
    castw<<<240, 256, 0, stream>>>(Wk, wk_bf);
    castw<<<240, 256, 0, stream>>>(Wv, wv_bf);
    castw<<<100, 256, 0, stream>>>(Wo, wo_bf);
    norm_tr<<<dim3(128, 10, 16), 256, 0, stream>>>(x, mr, gns, gnb, tok);
    gemm_qproj<<<dim3(64, 5, 16), 256, 0, stream>>>(tok, wq_bf, q_bf);
    kvproj<<<dim3(77, 16), 256, 0, stream>>>(ctx, wk_bf, wv_bf, k_bf, v_bf);
    attn<<<dim3(16, 8, 16), 256, 0, stream>>>(q_bf, k_bf, v_bf, tok);  // attn_out -> tok buffer
    gemm_oproj<<<dim3(64, 5, 16), 256, 0, stream>>>(tok, wo_bf, bo, x, out);
}

// Round 2
// 373.713 us; speedup vs baseline: 1.3860x; 1.3860x over previous
//
#include <hip/hip_runtime.h>
#include <hip/hip_bf16.h>
#include <stdint.h>

#define B_    16
#define C_    320
#define S_    4096
#define G_    32
#define LC    77
#define CTX   768
#define HEADS 8
#define HD    40

typedef __bf16 bf16x8_t __attribute__((ext_vector_type(8)));
typedef float  f32x4_t  __attribute__((ext_vector_type(4)));

__device__ __forceinline__ unsigned short f2bf(float f) {
    union { float f; unsigned int u; } v; v.f = f;
    unsigned int r = v.u + 0x7fffu + ((v.u >> 16) & 1u);
    return (unsigned short)(r >> 16);
}
__device__ __forceinline__ float bf2f(unsigned short h) {
    union { unsigned int u; float f; } v; v.u = ((unsigned int)h) << 16;
    return v.f;
}
__device__ __forceinline__ void unpack8(uint4 p, float* f) {
    f[0] = bf2f(p.x & 0xffffu); f[1] = bf2f(p.x >> 16);
    f[2] = bf2f(p.y & 0xffffu); f[3] = bf2f(p.y >> 16);
    f[4] = bf2f(p.z & 0xffffu); f[5] = bf2f(p.z >> 16);
    f[6] = bf2f(p.w & 0xffffu); f[7] = bf2f(p.w >> 16);
}

// ---------------------------------------------------------------- GN stats
__global__ __launch_bounds__(256) void gn_stats(const float* __restrict__ x,
                                                float2* __restrict__ mr) {
    int bg = blockIdx.x;
    const float4* p = (const float4*)(x + (size_t)bg * 40960);
    float s = 0.f, s2 = 0.f;
    for (int i = threadIdx.x; i < 10240; i += 256) {
        float4 v = p[i];
        s  += v.x + v.y + v.z + v.w;
        s2 += v.x * v.x + v.y * v.y + v.z * v.z + v.w * v.w;
    }
    for (int o = 32; o; o >>= 1) {
        s  += __shfl_down(s, o);
        s2 += __shfl_down(s2, o);
    }
    __shared__ float2 red[4];
    int lane = threadIdx.x & 63, wid = threadIdx.x >> 6;
    if (lane == 0) red[wid] = make_float2(s, s2);
    __syncthreads();
    if (threadIdx.x == 0) {
        float a = 0.f, c = 0.f;
        for (int i = 0; i < 4; i++) { a += red[i].x; c += red[i].y; }
        float mean = a / 40960.f;
        float var  = c / 40960.f - mean * mean;
        mr[bg] = make_float2(mean, rsqrtf(var + 1e-5f));
    }
}

// ---------------------------------------------------------------- weight cast
__global__ __launch_bounds__(256) void castw(const float* __restrict__ s,
                                             unsigned short* __restrict__ d) {
    int i = blockIdx.x * 256 + threadIdx.x;
    float4 v = ((const float4*)s)[i];
    ushort4 o;
    o.x = f2bf(v.x); o.y = f2bf(v.y); o.z = f2bf(v.z); o.w = f2bf(v.w);
    ((ushort4*)d)[i] = o;
}

// ---------------------------------------------------------------- normalize + transpose
__global__ __launch_bounds__(256) void norm_tr(const float* __restrict__ x,
                                               const float2* __restrict__ mr,
                                               const float* __restrict__ gns,
                                               const float* __restrict__ gnb,
                                               unsigned short* __restrict__ tok) {
    int s0 = blockIdx.x * 32, c0 = blockIdx.y * 32, b = blockIdx.z;
    __shared__ unsigned short t[32][33];
    int tx = threadIdx.x & 31, ty = threadIdx.x >> 5;
    #pragma unroll
    for (int i = 0; i < 4; i++) {
        int cl = i * 8 + ty;
        int c = c0 + cl;
        float2 m = mr[b * 32 + c / 10];
        float v = x[((size_t)(b * 320 + c)) * 4096 + s0 + tx];
        v = (v - m.x) * m.y * gns[c] + gnb[c];
        t[cl][tx] = f2bf(v);
    }
    __syncthreads();
    #pragma unroll
    for (int i = 0; i < 4; i++) {
        int sl = i * 8 + ty;
        tok[((size_t)b * 4096 + s0 + sl) * 320 + c0 + tx] = t[tx][sl];
    }
}

// ---------------------------------------------------------------- GEMM core (64x64 tile, K=320)
__device__ __forceinline__ void gemm_core(const unsigned short* __restrict__ Ab,
                                          const unsigned short* __restrict__ Wb,
                                          unsigned short la[64][32],
                                          unsigned short lb[64][32],
                                          f32x4_t acc[2][2]) {
    int tid = threadIdx.x, lane = tid & 63, wid = tid >> 6;
    int wm = wid >> 1, wn = wid & 1;
    int lr = tid >> 2, lc = (tid & 3) * 8;
    int fr = lane & 15, kk = (lane >> 4) * 8;
    for (int k0 = 0; k0 < 320; k0 += 32) {
        *(uint4*)&la[lr][lc] = *(const uint4*)&Ab[(size_t)lr * 320 + k0 + lc];
        *(uint4*)&lb[lr][lc] = *(const uint4*)&Wb[(size_t)lr * 320 + k0 + lc];
        __syncthreads();
        bf16x8_t a0 = *(const bf16x8_t*)&la[wm * 32 + fr][kk];
        bf16x8_t a1 = *(const bf16x8_t*)&la[wm * 32 + 16 + fr][kk];
        bf16x8_t b0 = *(const bf16x8_t*)&lb[wn * 32 + fr][kk];
        bf16x8_t b1 = *(const bf16x8_t*)&lb[wn * 32 + 16 + fr][kk];
        acc[0][0] = __builtin_amdgcn_mfma_f32_16x16x32_bf16(a0, b0, acc[0][0], 0, 0, 0);
        acc[0][1] = __builtin_amdgcn_mfma_f32_16x16x32_bf16(a0, b1, acc[0][1], 0, 0, 0);
        acc[1][0] = __builtin_amdgcn_mfma_f32_16x16x32_bf16(a1, b0, acc[1][0], 0, 0, 0);
        acc[1][1] = __builtin_amdgcn_mfma_f32_16x16x32_bf16(a1, b1, acc[1][1], 0, 0, 0);
        __syncthreads();
    }
}

__global__ __launch_bounds__(256) void gemm_qproj(const unsigned short* __restrict__ A,
                                                  const unsigned short* __restrict__ W,
                                                  unsigned short* __restrict__ Q) {
    __shared__ unsigned short la[64][32], lb[64][32];
    int bm = blockIdx.x, bn = blockIdx.y, b = blockIdx.z;
    const unsigned short* Ab = A + ((size_t)b * S_ + bm * 64) * 320;
    const unsigned short* Wb = W + (size_t)bn * 64 * 320;
    f32x4_t acc[2][2] = {};
    gemm_core(Ab, Wb, la, lb, acc);
    int tid = threadIdx.x, lane = tid & 63, wid = tid >> 6;
    int wm = wid >> 1, wn = wid & 1;
    int fr = lane & 15, rg = (lane >> 4) * 4;
    #pragma unroll
    for (int mf = 0; mf < 2; mf++)
        #pragma unroll
        for (int nf = 0; nf < 2; nf++)
            #pragma unroll
            for (int r = 0; r < 4; r++) {
                int row = bm * 64 + wm * 32 + mf * 16 + rg + r;
                int col = bn * 64 + wn * 32 + nf * 16 + fr;
                Q[((size_t)b * S_ + row) * 320 + col] = f2bf(acc[mf][nf][r]);
            }
}

__global__ __launch_bounds__(256) void gemm_oproj(const unsigned short* __restrict__ A,
                                                  const unsigned short* __restrict__ W,
                                                  const float* __restrict__ bo,
                                                  const float* __restrict__ resid,
                                                  float* __restrict__ out) {
    __shared__ unsigned short la[64][32], lb[64][32];
    __shared__ float lt[64][65];
    int bm = blockIdx.x, bn = blockIdx.y, b = blockIdx.z;
    const unsigned short* Ab = A + ((size_t)b * S_ + bm * 64) * 320;
    const unsigned short* Wb = W + (size_t)bn * 64 * 320;
    f32x4_t acc[2][2] = {};
    gemm_core(Ab, Wb, la, lb, acc);
    int tid = threadIdx.x, lane = tid & 63, wid = tid >> 6;
    int wm = wid >> 1, wn = wid & 1;
    int fr = lane & 15, rg = (lane >> 4) * 4;
    #pragma unroll
    for (int mf = 0; mf < 2; mf++)
        #pragma unroll
        for (int nf = 0; nf < 2; nf++)
            #pragma unroll
            for (int r = 0; r < 4; r++)
                lt[wm * 32 + mf * 16 + rg + r][wn * 32 + nf * 16 + fr] = acc[mf][nf][r];
    __syncthreads();
    #pragma unroll
    for (int p = 0; p < 16; p++) {
        int nl = p * 4 + (tid >> 6);
        int sl = tid & 63;
        int n = bn * 64 + nl, s = bm * 64 + sl;
        size_t idx = ((size_t)b * 320 + n) * 4096 + s;
        out[idx] = lt[sl][nl] + bo[n] + resid[idx];
    }
}

// ---------------------------------------------------------------- K/V projection (small)
__global__ __launch_bounds__(256) void kvproj(const float* __restrict__ ctx,
                                              const unsigned short* __restrict__ wk,
                                              const unsigned short* __restrict__ wv,
                                              unsigned short* __restrict__ k,
                                              unsigned short* __restrict__ v) {
    int l = blockIdx.x, b = blockIdx.y;
    __shared__ float cl[CTX];
    const float* cp = ctx + ((size_t)b * LC + l) * CTX;
    for (int i = threadIdx.x; i < CTX; i += 256) cl[i] = cp[i];
    __syncthreads();
    for (int e = threadIdx.x; e < 640; e += 256) {
        const unsigned short* w;
        unsigned short* dst;
        if (e < 320) { w = wk + (size_t)e * CTX;        dst = k + ((size_t)b * LC + l) * 320 + e; }
        else         { w = wv + (size_t)(e - 320) * CTX; dst = v + ((size_t)b * LC + l) * 320 + (e - 320); }
        float acc = 0.f;
        for (int kk = 0; kk < CTX; kk += 8) {
            uint4 pw = *(const uint4*)&w[kk];
            float wf[8]; unpack8(pw, wf);
            #pragma unroll
            for (int j = 0; j < 8; j++) acc += wf[j] * cl[kk + j];
        }
        *dst = f2bf(acc);
    }
}

// ---------------------------------------------------------------- MFMA attention
// block = 4 waves; 64 q-rows per block (16 per wave). K/V head-slice in LDS.
// scores: mfma(Q, K) with K-dim padded 40->64; single-shot softmax (Lc=77);
// P -> LDS (bf16) -> PV mfma with kv padded 77->96, d padded 40->48.
__global__ __launch_bounds__(256) void attn_mfma(const unsigned short* __restrict__ q,
                                                 const unsigned short* __restrict__ k,
                                                 const unsigned short* __restrict__ v,
                                                 unsigned short* __restrict__ o) {
    __shared__ unsigned short Qs[64][72];   //  9216 B  (q rows x k-dim padded)
    __shared__ unsigned short Ks[80][72];   // 11520 B  (kv rows x k-dim padded)
    __shared__ unsigned short Vt[48][104];  //  9984 B  (d rows x kv padded)
    __shared__ unsigned short Ps[64][100];  // 12800 B  (q rows x kv padded)

    int tid = threadIdx.x;
    int qt = blockIdx.x, h = blockIdx.y, b = blockIdx.z;
    int q0 = qt * 64;

    // zero everything (pads must be 0 to avoid NaN poisoning in MFMA)
    {
        unsigned int* p = (unsigned int*)&Qs[0][0];
        for (int i = tid; i < 2304; i += 256) p[i] = 0;
        p = (unsigned int*)&Ks[0][0];
        for (int i = tid; i < 2880; i += 256) p[i] = 0;
        p = (unsigned int*)&Vt[0][0];
        for (int i = tid; i < 2496; i += 256) p[i] = 0;
        p = (unsigned int*)&Ps[0][0];
        for (int i = tid; i < 3200; i += 256) p[i] = 0;
    }
    __syncthreads();
    // stage Q tile: 64 rows x 5 segs of 8 bf16
    for (int idx = tid; idx < 64 * 5; idx += 256) {
        int r = idx / 5, sg = idx % 5;
        *(uint4*)&Qs[r][sg * 8] =
            *(const uint4*)&q[((size_t)(b * S_ + q0 + r)) * 320 + h * HD + sg * 8];
    }
    // stage K: 77 rows x 5 segs
    for (int idx = tid; idx < 77 * 5; idx += 256) {
        int r = idx / 5, sg = idx % 5;
        *(uint4*)&Ks[r][sg * 8] =
            *(const uint4*)&k[((size_t)(b * LC + r)) * 320 + h * HD + sg * 8];
    }
    // stage V transposed: Vt[d][kv]
    for (int idx = tid; idx < 77 * 5; idx += 256) {
        int r = idx / 5, sg = idx % 5;
        uint4 pv = *(const uint4*)&v[((size_t)(b * LC + r)) * 320 + h * HD + sg * 8];
        unsigned short e[8];
        *(uint4*)e = pv;
        #pragma unroll
        for (int j = 0; j < 8; j++) Vt[sg * 8 + j][r] = e[j];
    }
    __syncthreads();

    int lane = tid & 63, wv = tid >> 6;
    int fr = lane & 15, fg = lane >> 4;

    // ---- scores: S = Q K^T  (5 kv-frags x 2 k-steps)
    f32x4_t sc[5];
    #pragma unroll
    for (int nf = 0; nf < 5; nf++) sc[nf] = (f32x4_t){0.f, 0.f, 0.f, 0.f};
    #pragma unroll
    for (int ks = 0; ks < 2; ks++) {
        bf16x8_t a = *(const bf16x8_t*)&Qs[wv * 16 + fr][ks * 32 + fg * 8];
        #pragma unroll
        for (int nf = 0; nf < 5; nf++) {
            bf16x8_t bb = *(const bf16x8_t*)&Ks[nf * 16 + fr][ks * 32 + fg * 8];
            sc[nf] = __builtin_amdgcn_mfma_f32_16x16x32_bf16(a, bb, sc[nf], 0, 0, 0);
        }
    }

    // ---- masked single-shot softmax (rows held: q_local = fg*4+r, col = nf*16+fr)
    const float scale = 0.15811388300841898f;  // 1/sqrt(40)
    float mx[4], sm[4];
    #pragma unroll
    for (int r = 0; r < 4; r++) {
        float m = -1e30f;
        #pragma unroll
        for (int nf = 0; nf < 5; nf++) {
            float s = sc[nf][r] * scale;
            if (nf * 16 + fr >= LC) s = -1e30f;
            sc[nf][r] = s;
            m = fmaxf(m, s);
        }
        mx[r] = m;
    }
    #pragma unroll
    for (int off = 1; off < 16; off <<= 1) {
        #pragma unroll
        for (int r = 0; r < 4; r++) mx[r] = fmaxf(mx[r], __shfl_xor(mx[r], off));
    }
    #pragma unroll
    for (int r = 0; r < 4; r++) {
        float s = 0.f;
        #pragma unroll
        for (int nf = 0; nf < 5; nf++) {
            float p = __expf(sc[nf][r] - mx[r]);
            sc[nf][r] = p;
            s += p;
        }
        sm[r] = s;
    }
    #pragma unroll
    for (int off = 1; off < 16; off <<= 1) {
        #pragma unroll
        for (int r = 0; r < 4; r++) sm[r] += __shfl_xor(sm[r], off);
    }

    // ---- P -> LDS (per-wave-private 16 rows; no cross-wave sharing)
    #pragma unroll
    for (int nf = 0; nf < 5; nf++)
        #pragma unroll
        for (int r = 0; r < 4; r++)
            Ps[wv * 16 + fg * 4 + r][nf * 16 + fr] = f2bf(sc[nf][r]);

    // ---- PV: out = P V  (3 d-frags x 3 k-steps over kv)
    f32x4_t ov[3];
    #pragma unroll
    for (int nf = 0; nf < 3; nf++) ov[nf] = (f32x4_t){0.f, 0.f, 0.f, 0.f};
    #pragma unroll
    for (int ks = 0; ks < 3; ks++) {
        bf16x8_t a = *(const bf16x8_t*)&Ps[wv * 16 + fr][ks * 32 + fg * 8];
        #pragma unroll
        for (int nf = 0; nf < 3; nf++) {
            bf16x8_t bb = *(const bf16x8_t*)&Vt[nf * 16 + fr][ks * 32 + fg * 8];
            ov[nf] = __builtin_amdgcn_mfma_f32_16x16x32_bf16(a, bb, ov[nf], 0, 0, 0);
        }
    }

    // ---- normalize + store (row = fg*4+r matches softmax row mapping)
    float inv[4];
    #pragma unroll
    for (int r = 0; r < 4; r++) inv[r] = 1.f / sm[r];
    #pragma unroll
    for (int nf = 0; nf < 3; nf++) {
        int d = nf * 16 + fr;
        if (d < HD) {
            #pragma unroll
            for (int r = 0; r < 4; r++) {
                int qrow = q0 + wv * 16 + fg * 4 + r;
                o[((size_t)(b * S_ + qrow)) * 320 + h * HD + d] = f2bf(ov[nf][r] * inv[r]);
            }
        }
    }
}

// ---------------------------------------------------------------- launch
extern "C" void kernel_launch(void* const* d_in, const int* in_sizes, int n_in,
                              void* d_out, int out_size, void* d_ws, size_t ws_size,
                              hipStream_t stream) {
    const float* x    = (const float*)d_in[0];
    const float* ctx  = (const float*)d_in[1];
    const float* Wq   = (const float*)d_in[2];
    const float* Wk   = (const float*)d_in[3];
    const float* Wv   = (const float*)d_in[4];
    const float* Wo   = (const float*)d_in[5];
    const float* bo   = (const float*)d_in[6];
    const float* gns  = (const float*)d_in[7];
    const float* gnb  = (const float*)d_in[8];
    float* out = (float*)d_out;

    char* ws = (char*)d_ws;
    float2*         mr    = (float2*)(ws + 0);
    unsigned short* wq_bf = (unsigned short*)(ws + 4096);
    unsigned short* wk_bf = (unsigned short*)(ws + 208896);
    unsigned short* wv_bf = (unsigned short*)(ws + 700416);
    unsigned short* wo_bf = (unsigned short*)(ws + 1191936);
    unsigned short* k_bf  = (unsigned short*)(ws + 1396736);
    unsigned short* v_bf  = (unsigned short*)(ws + 2185216);
    unsigned short* tok   = (unsigned short*)(ws + 2973696);
    unsigned short* q_bf  = (unsigned short*)(ws + 44916736);

    gn_stats<<<512, 256, 0, stream>>>(x, mr);
    castw<<<100, 256, 0, stream>>>(Wq, wq_bf);
    castw<<<240, 256, 0, stream>>>(Wk, wk_bf);
    castw<<<240, 256, 0, stream>>>(Wv, wv_bf);
    castw<<<100, 256, 0, stream>>>(Wo, wo_bf);
    norm_tr<<<dim3(128, 10, 16), 256, 0, stream>>>(x, mr, gns, gnb, tok);
    gemm_qproj<<<dim3(64, 5, 16), 256, 0, stream>>>(tok, wq_bf, q_bf);
    kvproj<<<dim3(77, 16), 256, 0, stream>>>(ctx, wk_bf, wv_bf, k_bf, v_bf);
    attn_mfma<<<dim3(64, 8, 16), 256, 0, stream>>>(q_bf, k_bf, v_bf, tok);
    gemm_oproj<<<dim3(64, 5, 16), 256, 0, stream>>>(tok, wo_bf, bo, x, out);
}

// Round 3
// 240.150 us; speedup vs baseline: 2.1569x; 1.5562x over previous
//
#include <hip/hip_runtime.h>
#include <hip/hip_bf16.h>
#include <stdint.h>

#define B_    16
#define C_    320
#define S_    4096
#define G_    32
#define LC    77
#define CTX   768
#define HEADS 8
#define HD    40

typedef __bf16 bf16x8_t __attribute__((ext_vector_type(8)));
typedef float  f32x4_t  __attribute__((ext_vector_type(4)));

__device__ __forceinline__ unsigned short f2bf(float f) {
    union { float f; unsigned int u; } v; v.f = f;
    unsigned int r = v.u + 0x7fffu + ((v.u >> 16) & 1u);
    return (unsigned short)(r >> 16);
}
__device__ __forceinline__ float bf2f(unsigned short h) {
    union { unsigned int u; float f; } v; v.u = ((unsigned int)h) << 16;
    return v.f;
}

// ---------------------------------------------------------------- GN stats
__global__ __launch_bounds__(256) void gn_stats(const float* __restrict__ x,
                                                float2* __restrict__ mr) {
    int bg = blockIdx.x;
    const float4* p = (const float4*)(x + (size_t)bg * 40960);
    float s = 0.f, s2 = 0.f;
    for (int i = threadIdx.x; i < 10240; i += 256) {
        float4 v = p[i];
        s  += v.x + v.y + v.z + v.w;
        s2 += v.x * v.x + v.y * v.y + v.z * v.z + v.w * v.w;
    }
    for (int o = 32; o; o >>= 1) {
        s  += __shfl_down(s, o);
        s2 += __shfl_down(s2, o);
    }
    __shared__ float2 red[4];
    int lane = threadIdx.x & 63, wid = threadIdx.x >> 6;
    if (lane == 0) red[wid] = make_float2(s, s2);
    __syncthreads();
    if (threadIdx.x == 0) {
        float a = 0.f, c = 0.f;
        for (int i = 0; i < 4; i++) { a += red[i].x; c += red[i].y; }
        float mean = a / 40960.f;
        float var  = c / 40960.f - mean * mean;
        mr[bg] = make_float2(mean, rsqrtf(var + 1e-5f));
    }
}

// ---------------------------------------------------------------- weight cast
__global__ __launch_bounds__(256) void castw(const float* __restrict__ s,
                                             unsigned short* __restrict__ d) {
    int i = blockIdx.x * 256 + threadIdx.x;
    float4 v = ((const float4*)s)[i];
    ushort4 o;
    o.x = f2bf(v.x); o.y = f2bf(v.y); o.z = f2bf(v.z); o.w = f2bf(v.w);
    ((ushort4*)d)[i] = o;
}

// ---------------------------------------------------------------- normalize + transpose
__global__ __launch_bounds__(256) void norm_tr(const float* __restrict__ x,
                                               const float2* __restrict__ mr,
                                               const float* __restrict__ gns,
                                               const float* __restrict__ gnb,
                                               unsigned short* __restrict__ tok) {
    int s0 = blockIdx.x * 32, c0 = blockIdx.y * 32, b = blockIdx.z;
    __shared__ unsigned short t[32][33];
    int tx = threadIdx.x & 31, ty = threadIdx.x >> 5;
    #pragma unroll
    for (int i = 0; i < 4; i++) {
        int cl = i * 8 + ty;
        int c = c0 + cl;
        float2 m = mr[b * 32 + c / 10];
        float v = x[((size_t)(b * 320 + c)) * 4096 + s0 + tx];
        v = (v - m.x) * m.y * gns[c] + gnb[c];
        t[cl][tx] = f2bf(v);
    }
    __syncthreads();
    #pragma unroll
    for (int i = 0; i < 4; i++) {
        int sl = i * 8 + ty;
        tok[((size_t)b * 4096 + s0 + sl) * 320 + c0 + tx] = t[tx][sl];
    }
}

// ---------------------------------------------------------------- GEMM core (64x64 tile, K=320)
__device__ __forceinline__ void gemm_core(const unsigned short* __restrict__ Ab,
                                          const unsigned short* __restrict__ Wb,
                                          unsigned short la[64][32],
                                          unsigned short lb[64][32],
                                          f32x4_t acc[2][2]) {
    int tid = threadIdx.x, lane = tid & 63, wid = tid >> 6;
    int wm = wid >> 1, wn = wid & 1;
    int lr = tid >> 2, lc = (tid & 3) * 8;
    int fr = lane & 15, kk = (lane >> 4) * 8;
    for (int k0 = 0; k0 < 320; k0 += 32) {
        *(uint4*)&la[lr][lc] = *(const uint4*)&Ab[(size_t)lr * 320 + k0 + lc];
        *(uint4*)&lb[lr][lc] = *(const uint4*)&Wb[(size_t)lr * 320 + k0 + lc];
        __syncthreads();
        bf16x8_t a0 = *(const bf16x8_t*)&la[wm * 32 + fr][kk];
        bf16x8_t a1 = *(const bf16x8_t*)&la[wm * 32 + 16 + fr][kk];
        bf16x8_t b0 = *(const bf16x8_t*)&lb[wn * 32 + fr][kk];
        bf16x8_t b1 = *(const bf16x8_t*)&lb[wn * 32 + 16 + fr][kk];
        acc[0][0] = __builtin_amdgcn_mfma_f32_16x16x32_bf16(a0, b0, acc[0][0], 0, 0, 0);
        acc[0][1] = __builtin_amdgcn_mfma_f32_16x16x32_bf16(a0, b1, acc[0][1], 0, 0, 0);
        acc[1][0] = __builtin_amdgcn_mfma_f32_16x16x32_bf16(a1, b0, acc[1][0], 0, 0, 0);
        acc[1][1] = __builtin_amdgcn_mfma_f32_16x16x32_bf16(a1, b1, acc[1][1], 0, 0, 0);
        __syncthreads();
    }
}

__global__ __launch_bounds__(256) void gemm_qproj(const unsigned short* __restrict__ A,
                                                  const unsigned short* __restrict__ W,
                                                  unsigned short* __restrict__ Q) {
    __shared__ unsigned short la[64][32], lb[64][32];
    int bm = blockIdx.x, bn = blockIdx.y, b = blockIdx.z;
    const unsigned short* Ab = A + ((size_t)b * S_ + bm * 64) * 320;
    const unsigned short* Wb = W + (size_t)bn * 64 * 320;
    f32x4_t acc[2][2] = {};
    gemm_core(Ab, Wb, la, lb, acc);
    int tid = threadIdx.x, lane = tid & 63, wid = tid >> 6;
    int wm = wid >> 1, wn = wid & 1;
    int fr = lane & 15, rg = (lane >> 4) * 4;
    #pragma unroll
    for (int mf = 0; mf < 2; mf++)
        #pragma unroll
        for (int nf = 0; nf < 2; nf++)
            #pragma unroll
            for (int r = 0; r < 4; r++) {
                int row = bm * 64 + wm * 32 + mf * 16 + rg + r;
                int col = bn * 64 + wn * 32 + nf * 16 + fr;
                Q[((size_t)b * S_ + row) * 320 + col] = f2bf(acc[mf][nf][r]);
            }
}

__global__ __launch_bounds__(256) void gemm_oproj(const unsigned short* __restrict__ A,
                                                  const unsigned short* __restrict__ W,
                                                  const float* __restrict__ bo,
                                                  const float* __restrict__ resid,
                                                  float* __restrict__ out) {
    __shared__ unsigned short la[64][32], lb[64][32];
    __shared__ float lt[64][65];
    int bm = blockIdx.x, bn = blockIdx.y, b = blockIdx.z;
    const unsigned short* Ab = A + ((size_t)b * S_ + bm * 64) * 320;
    const unsigned short* Wb = W + (size_t)bn * 64 * 320;
    f32x4_t acc[2][2] = {};
    gemm_core(Ab, Wb, la, lb, acc);
    int tid = threadIdx.x, lane = tid & 63, wid = tid >> 6;
    int wm = wid >> 1, wn = wid & 1;
    int fr = lane & 15, rg = (lane >> 4) * 4;
    #pragma unroll
    for (int mf = 0; mf < 2; mf++)
        #pragma unroll
        for (int nf = 0; nf < 2; nf++)
            #pragma unroll
            for (int r = 0; r < 4; r++)
                lt[wm * 32 + mf * 16 + rg + r][wn * 32 + nf * 16 + fr] = acc[mf][nf][r];
    __syncthreads();
    #pragma unroll
    for (int p = 0; p < 16; p++) {
        int nl = p * 4 + (tid >> 6);
        int sl = tid & 63;
        int n = bn * 64 + nl, s = bm * 64 + sl;
        size_t idx = ((size_t)b * 320 + n) * 4096 + s;
        out[idx] = lt[sl][nl] + bo[n] + resid[idx];
    }
}

// ---------------------------------------------------------------- K/V projection as MFMA GEMM
// A = ctx [1232 x 768] f32 (cast fused in staging); W = Wk/Wv [320 x 768] f32.
// out: k/v bf16 [1232 x 320]. M-tail: clamp loads, guard stores.
__global__ __launch_bounds__(256) void kvproj_gemm(const float* __restrict__ ctx,
                                                   const float* __restrict__ Wk,
                                                   const float* __restrict__ Wv,
                                                   unsigned short* __restrict__ kout,
                                                   unsigned short* __restrict__ vout) {
    __shared__ unsigned short la[64][32], lb[64][32];
    int bm = blockIdx.x, bn = blockIdx.y;
    const float* Wb = (bn < 5) ? (Wk + (size_t)bn * 64 * CTX)
                               : (Wv + (size_t)(bn - 5) * 64 * CTX);
    unsigned short* dst = (bn < 5) ? kout : vout;
    int ncol0 = (bn < 5 ? bn : bn - 5) * 64;

    int tid = threadIdx.x, lane = tid & 63, wid = tid >> 6;
    int wm = wid >> 1, wn = wid & 1;
    int lr = tid >> 2, lc = (tid & 3) * 8;
    int fr = lane & 15, kk = (lane >> 4) * 8;
    int arow = bm * 64 + lr; if (arow > 1231) arow = 1231;
    const float* ap = ctx + (size_t)arow * CTX;
    const float* wp = Wb + (size_t)lr * CTX;

    f32x4_t acc[2][2] = {};
    for (int k0 = 0; k0 < CTX; k0 += 32) {
        float4 a4 = *(const float4*)&ap[k0 + lc];
        float4 a5 = *(const float4*)&ap[k0 + lc + 4];
        float4 w4 = *(const float4*)&wp[k0 + lc];
        float4 w5 = *(const float4*)&wp[k0 + lc + 4];
        ushort4 pa0 = { f2bf(a4.x), f2bf(a4.y), f2bf(a4.z), f2bf(a4.w) };
        ushort4 pa1 = { f2bf(a5.x), f2bf(a5.y), f2bf(a5.z), f2bf(a5.w) };
        ushort4 pw0 = { f2bf(w4.x), f2bf(w4.y), f2bf(w4.z), f2bf(w4.w) };
        ushort4 pw1 = { f2bf(w5.x), f2bf(w5.y), f2bf(w5.z), f2bf(w5.w) };
        *(ushort4*)&la[lr][lc]     = pa0;
        *(ushort4*)&la[lr][lc + 4] = pa1;
        *(ushort4*)&lb[lr][lc]     = pw0;
        *(ushort4*)&lb[lr][lc + 4] = pw1;
        __syncthreads();
        bf16x8_t a0 = *(const bf16x8_t*)&la[wm * 32 + fr][kk];
        bf16x8_t a1 = *(const bf16x8_t*)&la[wm * 32 + 16 + fr][kk];
        bf16x8_t b0 = *(const bf16x8_t*)&lb[wn * 32 + fr][kk];
        bf16x8_t b1 = *(const bf16x8_t*)&lb[wn * 32 + 16 + fr][kk];
        acc[0][0] = __builtin_amdgcn_mfma_f32_16x16x32_bf16(a0, b0, acc[0][0], 0, 0, 0);
        acc[0][1] = __builtin_amdgcn_mfma_f32_16x16x32_bf16(a0, b1, acc[0][1], 0, 0, 0);
        acc[1][0] = __builtin_amdgcn_mfma_f32_16x16x32_bf16(a1, b0, acc[1][0], 0, 0, 0);
        acc[1][1] = __builtin_amdgcn_mfma_f32_16x16x32_bf16(a1, b1, acc[1][1], 0, 0, 0);
        __syncthreads();
    }
    int rg = (lane >> 4) * 4;
    #pragma unroll
    for (int mf = 0; mf < 2; mf++)
        #pragma unroll
        for (int nf = 0; nf < 2; nf++)
            #pragma unroll
            for (int r = 0; r < 4; r++) {
                int row = bm * 64 + wm * 32 + mf * 16 + rg + r;
                if (row < 1232) {
                    int col = ncol0 + wn * 32 + nf * 16 + fr;
                    dst[(size_t)row * 320 + col] = f2bf(acc[mf][nf][r]);
                }
            }
}

// ---------------------------------------------------------------- MFMA attention
__global__ __launch_bounds__(256) void attn_mfma(const unsigned short* __restrict__ q,
                                                 const unsigned short* __restrict__ k,
                                                 const unsigned short* __restrict__ v,
                                                 unsigned short* __restrict__ o) {
    __shared__ unsigned short Qs[64][72];
    __shared__ unsigned short Ks[80][72];
    __shared__ unsigned short Vt[48][104];
    __shared__ unsigned short Ps[64][100];

    int tid = threadIdx.x;
    int qt = blockIdx.x, h = blockIdx.y, b = blockIdx.z;
    int q0 = qt * 64;

    {
        unsigned int* p = (unsigned int*)&Qs[0][0];
        for (int i = tid; i < 2304; i += 256) p[i] = 0;
        p = (unsigned int*)&Ks[0][0];
        for (int i = tid; i < 2880; i += 256) p[i] = 0;
        p = (unsigned int*)&Vt[0][0];
        for (int i = tid; i < 2496; i += 256) p[i] = 0;
        p = (unsigned int*)&Ps[0][0];
        for (int i = tid; i < 3200; i += 256) p[i] = 0;
    }
    __syncthreads();
    for (int idx = tid; idx < 64 * 5; idx += 256) {
        int r = idx / 5, sg = idx % 5;
        *(uint4*)&Qs[r][sg * 8] =
            *(const uint4*)&q[((size_t)(b * S_ + q0 + r)) * 320 + h * HD + sg * 8];
    }
    for (int idx = tid; idx < 77 * 5; idx += 256) {
        int r = idx / 5, sg = idx % 5;
        *(uint4*)&Ks[r][sg * 8] =
            *(const uint4*)&k[((size_t)(b * LC + r)) * 320 + h * HD + sg * 8];
    }
    for (int idx = tid; idx < 77 * 5; idx += 256) {
        int r = idx / 5, sg = idx % 5;
        uint4 pv = *(const uint4*)&v[((size_t)(b * LC + r)) * 320 + h * HD + sg * 8];
        unsigned short e[8];
        *(uint4*)e = pv;
        #pragma unroll
        for (int j = 0; j < 8; j++) Vt[sg * 8 + j][r] = e[j];
    }
    __syncthreads();

    int lane = tid & 63, wv = tid >> 6;
    int fr = lane & 15, fg = lane >> 4;

    f32x4_t sc[5];
    #pragma unroll
    for (int nf = 0; nf < 5; nf++) sc[nf] = (f32x4_t){0.f, 0.f, 0.f, 0.f};
    #pragma unroll
    for (int ks = 0; ks < 2; ks++) {
        bf16x8_t a = *(const bf16x8_t*)&Qs[wv * 16 + fr][ks * 32 + fg * 8];
        #pragma unroll
        for (int nf = 0; nf < 5; nf++) {
            bf16x8_t bb = *(const bf16x8_t*)&Ks[nf * 16 + fr][ks * 32 + fg * 8];
            sc[nf] = __builtin_amdgcn_mfma_f32_16x16x32_bf16(a, bb, sc[nf], 0, 0, 0);
        }
    }

    const float scale = 0.15811388300841898f;  // 1/sqrt(40)
    float mx[4], sm[4];
    #pragma unroll
    for (int r = 0; r < 4; r++) {
        float m = -1e30f;
        #pragma unroll
        for (int nf = 0; nf < 5; nf++) {
            float s = sc[nf][r] * scale;
            if (nf * 16 + fr >= LC) s = -1e30f;
            sc[nf][r] = s;
            m = fmaxf(m, s);
        }
        mx[r] = m;
    }
    #pragma unroll
    for (int off = 1; off < 16; off <<= 1) {
        #pragma unroll
        for (int r = 0; r < 4; r++) mx[r] = fmaxf(mx[r], __shfl_xor(mx[r], off));
    }
    #pragma unroll
    for (int r = 0; r < 4; r++) {
        float s = 0.f;
        #pragma unroll
        for (int nf = 0; nf < 5; nf++) {
            float p = __expf(sc[nf][r] - mx[r]);
            sc[nf][r] = p;
            s += p;
        }
        sm[r] = s;
    }
    #pragma unroll
    for (int off = 1; off < 16; off <<= 1) {
        #pragma unroll
        for (int r = 0; r < 4; r++) sm[r] += __shfl_xor(sm[r], off);
    }

    #pragma unroll
    for (int nf = 0; nf < 5; nf++)
        #pragma unroll
        for (int r = 0; r < 4; r++)
            Ps[wv * 16 + fg * 4 + r][nf * 16 + fr] = f2bf(sc[nf][r]);

    f32x4_t ov[3];
    #pragma unroll
    for (int nf = 0; nf < 3; nf++) ov[nf] = (f32x4_t){0.f, 0.f, 0.f, 0.f};
    #pragma unroll
    for (int ks = 0; ks < 3; ks++) {
        bf16x8_t a = *(const bf16x8_t*)&Ps[wv * 16 + fr][ks * 32 + fg * 8];
        #pragma unroll
        for (int nf = 0; nf < 3; nf++) {
            bf16x8_t bb = *(const bf16x8_t*)&Vt[nf * 16 + fr][ks * 32 + fg * 8];
            ov[nf] = __builtin_amdgcn_mfma_f32_16x16x32_bf16(a, bb, ov[nf], 0, 0, 0);
        }
    }

    float inv[4];
    #pragma unroll
    for (int r = 0; r < 4; r++) inv[r] = 1.f / sm[r];
    #pragma unroll
    for (int nf = 0; nf < 3; nf++) {
        int d = nf * 16 + fr;
        if (d < HD) {
            #pragma unroll
            for (int r = 0; r < 4; r++) {
                int qrow = q0 + wv * 16 + fg * 4 + r;
                o[((size_t)(b * S_ + qrow)) * 320 + h * HD + d] = f2bf(ov[nf][r] * inv[r]);
            }
        }
    }
}

// ---------------------------------------------------------------- launch
extern "C" void kernel_launch(void* const* d_in, const int* in_sizes, int n_in,
                              void* d_out, int out_size, void* d_ws, size_t ws_size,
                              hipStream_t stream) {
    const float* x    = (const float*)d_in[0];
    const float* ctx  = (const float*)d_in[1];
    const float* Wq   = (const float*)d_in[2];
    const float* Wk   = (const float*)d_in[3];
    const float* Wv   = (const float*)d_in[4];
    const float* Wo   = (const float*)d_in[5];
    const float* bo   = (const float*)d_in[6];
    const float* gns  = (const float*)d_in[7];
    const float* gnb  = (const float*)d_in[8];
    float* out = (float*)d_out;

    char* ws = (char*)d_ws;
    float2*         mr    = (float2*)(ws + 0);
    unsigned short* wq_bf = (unsigned short*)(ws + 4096);
    unsigned short* wo_bf = (unsigned short*)(ws + 1191936);
    unsigned short* k_bf  = (unsigned short*)(ws + 1396736);
    unsigned short* v_bf  = (unsigned short*)(ws + 2185216);
    unsigned short* tok   = (unsigned short*)(ws + 2973696);
    unsigned short* q_bf  = (unsigned short*)(ws + 44916736);

    gn_stats<<<512, 256, 0, stream>>>(x, mr);
    castw<<<100, 256, 0, stream>>>(Wq, wq_bf);
    castw<<<100, 256, 0, stream>>>(Wo, wo_bf);
    norm_tr<<<dim3(128, 10, 16), 256, 0, stream>>>(x, mr, gns, gnb, tok);
    gemm_qproj<<<dim3(64, 5, 16), 256, 0, stream>>>(tok, wq_bf, q_bf);
    kvproj_gemm<<<dim3(20, 10), 256, 0, stream>>>(ctx, Wk, Wv, k_bf, v_bf);
    attn_mfma<<<dim3(64, 8, 16), 256, 0, stream>>>(q_bf, k_bf, v_bf, tok);
    gemm_oproj<<<dim3(64, 5, 16), 256, 0, stream>>>(tok, wo_bf, bo, x, out);
}